// Round 1
// baseline (1930.942 us; speedup 1.0000x reference)
//
#include <hip/hip_runtime.h>
#include <hip/hip_bf16.h>

static constexpr int Bn = 8, Cc = 288, Hh = 48, Ww = 48;
static constexpr int HW = Hh * Ww;          // 2304
static constexpr int Mtot = Bn * HW;        // 18432
static constexpr int NH = 9, HD = 32;
static constexpr int Cff = 2592;

// ---------------------------------------------------------------- transpose in
// x (B, C, H, W) -> xl (M=B*H*W, C) pixel-major
__global__ __launch_bounds__(256) void transpose_in(const float* __restrict__ x,
                                                    float* __restrict__ xl) {
    __shared__ float tile[32][33];
    int b = blockIdx.z;
    int c0 = blockIdx.y * 32;
    int p0 = blockIdx.x * 32;
    int tx = threadIdx.x, ty = threadIdx.y;   // block (32,8)
#pragma unroll
    for (int q = 0; q < 4; ++q) {
        int c = c0 + ty + q * 8;
        tile[ty + q * 8][tx] = x[((size_t)b * Cc + c) * HW + p0 + tx];
    }
    __syncthreads();
#pragma unroll
    for (int q = 0; q < 4; ++q) {
        int p = p0 + ty + q * 8;
        xl[((size_t)b * HW + p) * Cc + c0 + tx] = tile[tx][ty + q * 8];
    }
}

// ---------------------------------------------------------------- weight repack
// Wqkv[c][g*288 + h*32 + d] = W_g[h][c][d]   (288 x 864)
__global__ __launch_bounds__(256) void repack_qkv(const float* __restrict__ WQ,
                                                  const float* __restrict__ WK,
                                                  const float* __restrict__ WV,
                                                  float* __restrict__ Wqkv) {
    int t = blockIdx.x * 256 + threadIdx.x;
    if (t >= Cc * 3 * Cc) return;
    int c = t / (3 * Cc);
    int r = t % (3 * Cc);
    int g = r / Cc;
    int hd_ = r % Cc;
    int h = hd_ / HD, d = hd_ % HD;
    const float* W = (g == 0) ? WQ : ((g == 1) ? WK : WV);
    Wqkv[t] = W[((size_t)h * Cc + c) * HD + d];
}

// Wout (Ccols x R) with Wout[c][n] = Win[n][c], Win is (R x Ccols)
__global__ __launch_bounds__(256) void repack_t(const float* __restrict__ Win,
                                                float* __restrict__ Wout,
                                                int R, int Ccols) {
    int t = blockIdx.x * 256 + threadIdx.x;
    if (t >= R * Ccols) return;
    int c = t / R;
    int n = t % R;
    Wout[t] = Win[(size_t)n * Ccols + c];
}

// ---------------------------------------------------------------- fp32 GEMM
// C (MxN) = A (MxK, row-major) * B (KxN, row-major) [+bias][relu]
// Requirements: M % 64 == 0, K % 16 == 0. N arbitrary (bounds-checked).
template <bool BIAS, bool RELU>
__global__ __launch_bounds__(256) void gemm_f32(const float* __restrict__ A,
                                                const float* __restrict__ B,
                                                const float* __restrict__ bias,
                                                float* __restrict__ C,
                                                int M, int N, int K) {
    __shared__ float As[16][64];   // As[k][m]
    __shared__ float Bs[16][64];   // Bs[k][n]
    const int tid = threadIdx.x;
    const int bm = blockIdx.y << 6;
    const int bn = blockIdx.x << 6;
    const int tm = (tid >> 4) << 2;
    const int tn = (tid & 15) << 2;
    const int arow = tid >> 2;          // 0..63
    const int akk  = (tid & 3) << 2;    // 0,4,8,12
    const int bkk  = tid >> 4;          // 0..15
    const int bnn  = (tid & 15) << 2;   // 0..60
    const float* Aptr = A + (size_t)(bm + arow) * K + akk;
    float acc[4][4] = {};
    for (int k0 = 0; k0 < K; k0 += 16) {
        float4 av = *(const float4*)(Aptr + k0);
        float4 bv;
        const int bcol = bn + bnn;
        const float* Bp = B + (size_t)(k0 + bkk) * N + bcol;
        if (bcol + 3 < N) {
            bv = *(const float4*)Bp;
        } else {
            bv.x = (bcol + 0 < N) ? Bp[0] : 0.f;
            bv.y = (bcol + 1 < N) ? Bp[1] : 0.f;
            bv.z = (bcol + 2 < N) ? Bp[2] : 0.f;
            bv.w = (bcol + 3 < N) ? Bp[3] : 0.f;
        }
        __syncthreads();   // previous iteration's compute done
        As[akk + 0][arow] = av.x;
        As[akk + 1][arow] = av.y;
        As[akk + 2][arow] = av.z;
        As[akk + 3][arow] = av.w;
        *(float4*)&Bs[bkk][bnn] = bv;
        __syncthreads();
#pragma unroll
        for (int kk = 0; kk < 16; ++kk) {
            float4 a = *(const float4*)&As[kk][tm];
            float4 b = *(const float4*)&Bs[kk][tn];
            acc[0][0] += a.x * b.x; acc[0][1] += a.x * b.y; acc[0][2] += a.x * b.z; acc[0][3] += a.x * b.w;
            acc[1][0] += a.y * b.x; acc[1][1] += a.y * b.y; acc[1][2] += a.y * b.z; acc[1][3] += a.y * b.w;
            acc[2][0] += a.z * b.x; acc[2][1] += a.z * b.y; acc[2][2] += a.z * b.z; acc[2][3] += a.z * b.w;
            acc[3][0] += a.w * b.x; acc[3][1] += a.w * b.y; acc[3][2] += a.w * b.z; acc[3][3] += a.w * b.w;
        }
    }
#pragma unroll
    for (int i = 0; i < 4; ++i) {
        const int row = bm + tm + i;   // M multiple of 64 -> always valid
#pragma unroll
        for (int j = 0; j < 4; ++j) {
            const int col = bn + tn + j;
            if (col < N) {
                float v = acc[i][j];
                if (BIAS) v += bias[col];
                if (RELU) v = fmaxf(v, 0.f);
                C[(size_t)row * N + col] = v;
            }
        }
    }
}

// ---------------------------------------------------------------- attention
// qkv (M x 864): [0:288)=Q, [288:576)=K, [576:864)=V, channel = h*32+d
// 32 lanes per (pixel, head). Interior pixels only; aout border pre-zeroed.
__global__ __launch_bounds__(256) void attn_kernel(const float* __restrict__ qkv,
                                                   float* __restrict__ aout) {
    int t = blockIdx.x * 256 + threadIdx.x;
    int d = t & 31;
    int ph = t >> 5;
    if (ph >= 16928 * 9) return;
    int h = ph % 9;
    int pix = ph / 9;
    int b = pix / (46 * 46);
    int r = pix % (46 * 46);
    int i = r / 46 + 1;
    int j = r % 46 + 1;
    int m = b * HW + i * Ww + j;
    int hd = h * HD + d;
    float q = qkv[(size_t)m * 864 + hd];
    float logits[9];
    int mns[9];
#pragma unroll
    for (int n = 0; n < 9; ++n) {
        int di = n / 3, dj = n % 3;
        int mn = b * HW + (i - 1 + di) * Ww + (j - 1 + dj);
        mns[n] = mn;
        float kv = qkv[(size_t)mn * 864 + 288 + hd];
        float p = q * kv;
#pragma unroll
        for (int s = 16; s >= 1; s >>= 1) p += __shfl_xor(p, s);
        logits[n] = p * 0.17677669529663687f;   // 1/sqrt(32)
    }
    float mx = logits[0];
#pragma unroll
    for (int n = 1; n < 9; ++n) mx = fmaxf(mx, logits[n]);
    float w[9];
    float sum = 0.f;
#pragma unroll
    for (int n = 0; n < 9; ++n) { w[n] = expf(logits[n] - mx); sum += w[n]; }
    float inv = 1.f / sum;
    float o = 0.f;
#pragma unroll
    for (int n = 0; n < 9; ++n) o += w[n] * qkv[(size_t)mns[n] * 864 + 576 + hd];
    aout[(size_t)m * 288 + hd] = o * inv;
}

// ---------------------------------------------------------------- layernorm (+relu)
__global__ __launch_bounds__(256) void ln_relu(const float* __restrict__ in,
                                               const float* __restrict__ g,
                                               const float* __restrict__ bta,
                                               float* __restrict__ out) {
    int wid = (blockIdx.x * 256 + threadIdx.x) >> 6;   // pixel
    int lane = threadIdx.x & 63;
    if (wid >= Mtot) return;
    const float* row = in + (size_t)wid * Cc;
    float v[5];
    float sum = 0.f, sq = 0.f;
#pragma unroll
    for (int q = 0; q < 5; ++q) {
        int c = lane + q * 64;
        float x_ = (c < Cc) ? row[c] : 0.f;
        v[q] = x_; sum += x_; sq += x_ * x_;
    }
#pragma unroll
    for (int s = 32; s >= 1; s >>= 1) { sum += __shfl_xor(sum, s); sq += __shfl_xor(sq, s); }
    float mean = sum * (1.f / Cc);
    float var = sq * (1.f / Cc) - mean * mean;
    float rstd = rsqrtf(var + 1e-5f);
#pragma unroll
    for (int q = 0; q < 5; ++q) {
        int c = lane + q * 64;
        if (c < Cc) {
            float y = (v[q] - mean) * rstd * g[c] + bta[c];
            out[(size_t)wid * Cc + c] = fmaxf(y, 0.f);
        }
    }
}

// ---------------------------------------------------------------- final: LN2 + residual + relu + transpose out
__global__ __launch_bounds__(256) void final_kernel(const float* __restrict__ in,
                                                    const float* __restrict__ xl,
                                                    const float* __restrict__ g,
                                                    const float* __restrict__ bta,
                                                    float* __restrict__ out) {
    int wid = (blockIdx.x * 256 + threadIdx.x) >> 6;
    int lane = threadIdx.x & 63;
    if (wid >= Mtot) return;
    int b = wid / HW;
    int p = wid % HW;
    const float* row = in + (size_t)wid * Cc;
    float v[5];
    float sum = 0.f, sq = 0.f;
#pragma unroll
    for (int q = 0; q < 5; ++q) {
        int c = lane + q * 64;
        float x_ = (c < Cc) ? row[c] : 0.f;
        v[q] = x_; sum += x_; sq += x_ * x_;
    }
#pragma unroll
    for (int s = 32; s >= 1; s >>= 1) { sum += __shfl_xor(sum, s); sq += __shfl_xor(sq, s); }
    float mean = sum * (1.f / Cc);
    float var = sq * (1.f / Cc) - mean * mean;
    float rstd = rsqrtf(var + 1e-5f);
#pragma unroll
    for (int q = 0; q < 5; ++q) {
        int c = lane + q * 64;
        if (c < Cc) {
            float y = (v[q] - mean) * rstd * g[c] + bta[c];
            float res = xl[(size_t)wid * Cc + c];
            out[((size_t)b * Cc + c) * HW + p] = fmaxf(y + res, 0.f);
        }
    }
}

// ---------------------------------------------------------------- ws-too-small sentinel
__global__ void sentinel_kernel(float* out, float val) {
    out[threadIdx.x] = val;
}

extern "C" void kernel_launch(void* const* d_in, const int* in_sizes, int n_in,
                              void* d_out, int out_size, void* d_ws, size_t ws_size,
                              hipStream_t stream) {
    const float* x   = (const float*)d_in[0];
    const float* WQ  = (const float*)d_in[1];
    const float* WK  = (const float*)d_in[2];
    const float* WV  = (const float*)d_in[3];
    const float* WO  = (const float*)d_in[4];
    const float* f1w = (const float*)d_in[5];
    const float* f1b = (const float*)d_in[6];
    const float* f2w = (const float*)d_in[7];
    const float* f2b = (const float*)d_in[8];
    const float* g1  = (const float*)d_in[9];
    const float* b1  = (const float*)d_in[10];
    const float* g2  = (const float*)d_in[11];
    const float* b2  = (const float*)d_in[12];

    float* ws = (float*)d_ws;
    size_t off = 0;
    auto alloc = [&](size_t n) { float* p = ws + off; off += n; return p; };
    const int Mc = Mtot / 8;   // 2304 — FFN M-chunk
    float* xl   = alloc((size_t)Mtot * Cc);
    float* qkv  = alloc((size_t)Mtot * 3 * Cc);
    float* aout = alloc((size_t)Mtot * Cc);
    float* ywo  = alloc((size_t)Mtot * Cc);
    float* yln  = alloc((size_t)Mtot * Cc);
    float* f2o  = alloc((size_t)Mtot * Cc);
    float* mid  = alloc((size_t)Mc * Cff);
    float* wqkv = alloc((size_t)Cc * 3 * Cc);
    float* w1t  = alloc((size_t)Cc * Cff);
    float* w2t  = alloc((size_t)Cff * Cc);

    if (ws_size < off * sizeof(float)) {
        // scratch too small — emit distinctive sentinel so the failure is diagnosable
        sentinel_kernel<<<1, 256, 0, stream>>>((float*)d_out, (float)(off * sizeof(float)) * 1e-6f);
        return;
    }

    transpose_in<<<dim3(HW / 32, Cc / 32, Bn), dim3(32, 8), 0, stream>>>(x, xl);
    repack_qkv<<<(Cc * 3 * Cc + 255) / 256, 256, 0, stream>>>(WQ, WK, WV, wqkv);
    repack_t<<<(Cc * Cff + 255) / 256, 256, 0, stream>>>(f1w, w1t, Cff, Cc);
    repack_t<<<(Cff * Cc + 255) / 256, 256, 0, stream>>>(f2w, w2t, Cc, Cff);

    // QKV projection: (M x 288) * (288 x 864)
    gemm_f32<false, false><<<dim3((3 * Cc + 63) / 64, Mtot / 64), 256, 0, stream>>>(
        xl, wqkv, nullptr, qkv, Mtot, 3 * Cc, Cc);

    // attention (border rows of aout = 0 implements the zero-pad)
    hipMemsetAsync(aout, 0, (size_t)Mtot * Cc * sizeof(float), stream);
    attn_kernel<<<(16928 * 9 * 32) / 256, 256, 0, stream>>>(qkv, aout);

    // W_O: (M x 288) * (288 x 288)
    gemm_f32<false, false><<<dim3((Cc + 63) / 64, Mtot / 64), 256, 0, stream>>>(
        aout, WO, nullptr, ywo, Mtot, Cc, Cc);

    // LN1 + ReLU
    ln_relu<<<Mtot / 4, 256, 0, stream>>>(ywo, g1, b1, yln);

    // FFN, chunked over M to bound the 2592-wide intermediate
    for (int ch = 0; ch < 8; ++ch) {
        const float* Ain = yln + (size_t)ch * Mc * Cc;
        gemm_f32<true, true><<<dim3((Cff + 63) / 64, Mc / 64), 256, 0, stream>>>(
            Ain, w1t, f1b, mid, Mc, Cff, Cc);
        gemm_f32<true, false><<<dim3((Cc + 63) / 64, Mc / 64), 256, 0, stream>>>(
            mid, w2t, f2b, f2o + (size_t)ch * Mc * Cc, Mc, Cc, Cff);
    }

    // LN2 + residual + ReLU + transpose to (B, C, H, W)
    final_kernel<<<Mtot / 4, 256, 0, stream>>>(f2o, xl, g2, b2, (float*)d_out);
}

// Round 2
// 293.732 us; speedup vs baseline: 6.5738x; 6.5738x over previous
//
#include <hip/hip_runtime.h>
#include <hip/hip_bf16.h>

static constexpr int Bn = 8, Cc = 288, Hh = 48, Ww = 48;
static constexpr int HW = Hh * Ww;          // 2304
static constexpr int Mtot = Bn * HW;        // 18432
static constexpr int NH = 9, HD = 32;
static constexpr int Cff = 2592;

typedef __attribute__((ext_vector_type(8))) short bf16x8;
typedef __attribute__((ext_vector_type(4))) float f32x4;

typedef const __attribute__((address_space(1))) unsigned gmem_word;
typedef __attribute__((address_space(3))) unsigned lds_word;

__device__ __forceinline__ void gload16(const void* g, void* l) {
    // async global->LDS, 16B per lane; LDS dest = wave-uniform base + lane*16
    __builtin_amdgcn_global_load_lds((gmem_word*)g, (lds_word*)l, 16, 0, 0);
}

// ---------------------------------------------------------------- transpose in
// x (B, C, H, W) -> xl (M, C) f32  and  xlb (M, C) bf16
__global__ __launch_bounds__(256) void transpose_in(const float* __restrict__ x,
                                                    float* __restrict__ xl,
                                                    __hip_bfloat16* __restrict__ xlb) {
    __shared__ float tile[32][33];
    int b = blockIdx.z;
    int c0 = blockIdx.y * 32;
    int p0 = blockIdx.x * 32;
    int tx = threadIdx.x, ty = threadIdx.y;   // block (32,8)
#pragma unroll
    for (int q = 0; q < 4; ++q) {
        int c = c0 + ty + q * 8;
        tile[ty + q * 8][tx] = x[((size_t)b * Cc + c) * HW + p0 + tx];
    }
    __syncthreads();
#pragma unroll
    for (int q = 0; q < 4; ++q) {
        int p = p0 + ty + q * 8;
        float v = tile[tx][ty + q * 8];
        size_t idx = ((size_t)b * HW + p) * Cc + c0 + tx;
        xl[idx] = v;
        xlb[idx] = __float2bfloat16(v);
    }
}

// ---------------------------------------------------------------- weight repacks
// wqkvt[n][c] bf16, n = g*288 + h*32 + d, = W_g[h][c][d]   (864 x 288)
__global__ __launch_bounds__(256) void repack_qkvt(const float* __restrict__ WQ,
                                                   const float* __restrict__ WK,
                                                   const float* __restrict__ WV,
                                                   __hip_bfloat16* __restrict__ Wt) {
    int t = blockIdx.x * 256 + threadIdx.x;
    if (t >= 3 * Cc * Cc) return;
    int n = t / Cc;
    int c = t % Cc;
    int g = n / Cc;
    int r = n % Cc;
    int h = r / HD, d = r % HD;
    const float* W = (g == 0) ? WQ : ((g == 1) ? WK : WV);
    Wt[t] = __float2bfloat16(W[((size_t)h * Cc + c) * HD + d]);
}

// wot[n][c] = WO[c][n] bf16   (288 x 288)
__global__ __launch_bounds__(256) void repack_wot(const float* __restrict__ WO,
                                                  __hip_bfloat16* __restrict__ Wt) {
    int t = blockIdx.x * 256 + threadIdx.x;
    if (t >= Cc * Cc) return;
    int n = t / Cc;
    int c = t % Cc;
    Wt[t] = __float2bfloat16(WO[(size_t)c * Cc + n]);
}

// elementwise f32 -> bf16
__global__ __launch_bounds__(256) void cast_bf16(const float* __restrict__ in,
                                                 __hip_bfloat16* __restrict__ out, int n) {
    int t = blockIdx.x * 256 + threadIdx.x;
    if (t < n) out[t] = __float2bfloat16(in[t]);
}

// ---------------------------------------------------------------- bf16 MFMA GEMM
// C (MxN) = A (MxK bf16 row-major) * Bw^T, Bw is (NxK bf16 row-major) [+bias][relu]
// M%128==0, N%96==0, K%32==0. Tile 128x96, BK=32, 4 waves (2x2), wave tile 64x48.
template <bool OUT_BF16, bool BIAS, bool RELU>
__global__ __launch_bounds__(256) void gemm_mfma(const __hip_bfloat16* __restrict__ A,
                                                 const __hip_bfloat16* __restrict__ Bw,
                                                 const float* __restrict__ bias,
                                                 void* __restrict__ Cout,
                                                 int M, int N, int K) {
    __shared__ __hip_bfloat16 As[2][128 * 32];   // [row][k] 8KB each
    __shared__ __hip_bfloat16 Bs[2][96 * 32];    // [n][k]   6KB each
    const int tid = threadIdx.x;
    const int wave = tid >> 6, lane = tid & 63;
    const int l16 = lane & 15, lq = lane >> 4;
    const int wr = wave >> 1, wc = wave & 1;
    const int bm = blockIdx.y * 128;
    const int bn = blockIdx.x * 96;
    const int nt = K >> 5;

    f32x4 acc[4][3] = {};

    auto stage = [&](int buf, int t) {
        const int k0 = t << 5;
        // 14 chunks of 1KB (8 for A, 6 for B), round-robin over 4 waves
        for (int c = wave; c < 14; c += 4) {
            if (c < 8) {
                int elem = (c << 9) + lane * 8;        // element index in 128x32 tile
                int row = elem >> 5, kk = elem & 31;
                gload16(A + (size_t)(bm + row) * K + k0 + kk, &As[buf][c << 9]);
            } else {
                int elem = ((c - 8) << 9) + lane * 8;  // element index in 96x32 tile
                int row = elem >> 5, kk = elem & 31;
                gload16(Bw + (size_t)(bn + row) * K + k0 + kk, &Bs[buf][(c - 8) << 9]);
            }
        }
    };

    stage(0, 0);
    __syncthreads();   // drains vmcnt(0): tile 0 resident
    int cur = 0;
    for (int t = 0; t < nt; ++t) {
        if (t + 1 < nt) stage(cur ^ 1, t + 1);   // async prefetch next tile
        bf16x8 a[4], b[3];
#pragma unroll
        for (int m = 0; m < 4; ++m)
            a[m] = *(const bf16x8*)&As[cur][(wr * 64 + m * 16 + l16) * 32 + lq * 8];
#pragma unroll
        for (int n = 0; n < 3; ++n)
            b[n] = *(const bf16x8*)&Bs[cur][(wc * 48 + n * 16 + l16) * 32 + lq * 8];
#pragma unroll
        for (int m = 0; m < 4; ++m)
#pragma unroll
            for (int n = 0; n < 3; ++n)
                acc[m][n] = __builtin_amdgcn_mfma_f32_16x16x32_bf16(a[m], b[n], acc[m][n], 0, 0, 0);
        __syncthreads();   // drains vmcnt (prefetch landed) + guards buffer reuse
        cur ^= 1;
    }

    // epilogue: C row = bm + wr*64 + m*16 + lq*4 + r ; col = bn + wc*48 + n*16 + l16
#pragma unroll
    for (int m = 0; m < 4; ++m) {
#pragma unroll
        for (int n = 0; n < 3; ++n) {
            const int col = bn + wc * 48 + n * 16 + l16;
            const float bv = BIAS ? bias[col] : 0.f;
#pragma unroll
            for (int r = 0; r < 4; ++r) {
                const int row = bm + wr * 64 + m * 16 + lq * 4 + r;
                float v = acc[m][n][r] + bv;
                if (RELU) v = fmaxf(v, 0.f);
                if (OUT_BF16)
                    ((__hip_bfloat16*)Cout)[(size_t)row * N + col] = __float2bfloat16(v);
                else
                    ((float*)Cout)[(size_t)row * N + col] = v;
            }
        }
    }
}

// ---------------------------------------------------------------- attention
// qkv (M x 864 bf16): [0:288)=Q, [288:576)=K, [576:864)=V, channel = h*32+d
// 32 lanes per (pixel, head). Interior pixels only; aout border pre-zeroed.
__global__ __launch_bounds__(256) void attn_kernel(const __hip_bfloat16* __restrict__ qkv,
                                                   __hip_bfloat16* __restrict__ aout) {
    int t = blockIdx.x * 256 + threadIdx.x;
    int d = t & 31;
    int ph = t >> 5;
    if (ph >= 16928 * 9) return;
    int h = ph % 9;
    int pix = ph / 9;
    int b = pix / (46 * 46);
    int r = pix % (46 * 46);
    int i = r / 46 + 1;
    int j = r % 46 + 1;
    int m = b * HW + i * Ww + j;
    int hd = h * HD + d;
    float q = __bfloat162float(qkv[(size_t)m * 864 + hd]);
    float logits[9];
    int mns[9];
#pragma unroll
    for (int n = 0; n < 9; ++n) {
        int di = n / 3, dj = n % 3;
        int mn = b * HW + (i - 1 + di) * Ww + (j - 1 + dj);
        mns[n] = mn;
        float kv = __bfloat162float(qkv[(size_t)mn * 864 + 288 + hd]);
        float p = q * kv;
#pragma unroll
        for (int s = 16; s >= 1; s >>= 1) p += __shfl_xor(p, s);
        logits[n] = p * 0.17677669529663687f;   // 1/sqrt(32)
    }
    float mx = logits[0];
#pragma unroll
    for (int n = 1; n < 9; ++n) mx = fmaxf(mx, logits[n]);
    float w[9];
    float sum = 0.f;
#pragma unroll
    for (int n = 0; n < 9; ++n) { w[n] = expf(logits[n] - mx); sum += w[n]; }
    float inv = 1.f / sum;
    float o = 0.f;
#pragma unroll
    for (int n = 0; n < 9; ++n)
        o += w[n] * __bfloat162float(qkv[(size_t)mns[n] * 864 + 576 + hd]);
    aout[(size_t)m * Cc + hd] = __float2bfloat16(o * inv);
}

// ---------------------------------------------------------------- LN1 + ReLU (f32 in, bf16 out)
__global__ __launch_bounds__(256) void ln_relu(const float* __restrict__ in,
                                               const float* __restrict__ g,
                                               const float* __restrict__ bta,
                                               __hip_bfloat16* __restrict__ out) {
    int wid = (blockIdx.x * 256 + threadIdx.x) >> 6;   // pixel
    int lane = threadIdx.x & 63;
    if (wid >= Mtot) return;
    const float* row = in + (size_t)wid * Cc;
    float v[5];
    float sum = 0.f, sq = 0.f;
#pragma unroll
    for (int q = 0; q < 5; ++q) {
        int c = lane + q * 64;
        float x_ = (c < Cc) ? row[c] : 0.f;
        v[q] = x_; sum += x_; sq += x_ * x_;
    }
#pragma unroll
    for (int s = 32; s >= 1; s >>= 1) { sum += __shfl_xor(sum, s); sq += __shfl_xor(sq, s); }
    float mean = sum * (1.f / Cc);
    float var = sq * (1.f / Cc) - mean * mean;
    float rstd = rsqrtf(var + 1e-5f);
#pragma unroll
    for (int q = 0; q < 5; ++q) {
        int c = lane + q * 64;
        if (c < Cc) {
            float y = (v[q] - mean) * rstd * g[c] + bta[c];
            out[(size_t)wid * Cc + c] = __float2bfloat16(fmaxf(y, 0.f));
        }
    }
}

// ---------------------------------------------------------------- final: LN2 + residual + relu + transpose out
__global__ __launch_bounds__(256) void final_kernel(const float* __restrict__ in,
                                                    const float* __restrict__ xl,
                                                    const float* __restrict__ g,
                                                    const float* __restrict__ bta,
                                                    float* __restrict__ out) {
    int wid = (blockIdx.x * 256 + threadIdx.x) >> 6;
    int lane = threadIdx.x & 63;
    if (wid >= Mtot) return;
    int b = wid / HW;
    int p = wid % HW;
    const float* row = in + (size_t)wid * Cc;
    float v[5];
    float sum = 0.f, sq = 0.f;
#pragma unroll
    for (int q = 0; q < 5; ++q) {
        int c = lane + q * 64;
        float x_ = (c < Cc) ? row[c] : 0.f;
        v[q] = x_; sum += x_; sq += x_ * x_;
    }
#pragma unroll
    for (int s = 32; s >= 1; s >>= 1) { sum += __shfl_xor(sum, s); sq += __shfl_xor(sq, s); }
    float mean = sum * (1.f / Cc);
    float var = sq * (1.f / Cc) - mean * mean;
    float rstd = rsqrtf(var + 1e-5f);
#pragma unroll
    for (int q = 0; q < 5; ++q) {
        int c = lane + q * 64;
        if (c < Cc) {
            float y = (v[q] - mean) * rstd * g[c] + bta[c];
            float res = xl[(size_t)wid * Cc + c];
            out[((size_t)b * Cc + c) * HW + p] = fmaxf(y + res, 0.f);
        }
    }
}

// ---------------------------------------------------------------- ws-too-small sentinel
__global__ void sentinel_kernel(float* out, float val) {
    out[threadIdx.x] = val;
}

extern "C" void kernel_launch(void* const* d_in, const int* in_sizes, int n_in,
                              void* d_out, int out_size, void* d_ws, size_t ws_size,
                              hipStream_t stream) {
    const float* x   = (const float*)d_in[0];
    const float* WQ  = (const float*)d_in[1];
    const float* WK  = (const float*)d_in[2];
    const float* WV  = (const float*)d_in[3];
    const float* WO  = (const float*)d_in[4];
    const float* f1w = (const float*)d_in[5];
    const float* f1b = (const float*)d_in[6];
    const float* f2w = (const float*)d_in[7];
    const float* f2b = (const float*)d_in[8];
    const float* g1  = (const float*)d_in[9];
    const float* b1  = (const float*)d_in[10];
    const float* g2  = (const float*)d_in[11];
    const float* b2  = (const float*)d_in[12];

    char* ws = (char*)d_ws;
    size_t off = 0;
    auto alloc = [&](size_t bytes) { void* p = ws + off; off += (bytes + 255) & ~(size_t)255; return p; };

    float*          xl    = (float*)alloc((size_t)Mtot * Cc * 4);
    __hip_bfloat16* xlb   = (__hip_bfloat16*)alloc((size_t)Mtot * Cc * 2);   // aliased by aout later
    __hip_bfloat16* wqkvt = (__hip_bfloat16*)alloc((size_t)3 * Cc * Cc * 2);
    char*           big   = (char*)alloc((size_t)Mtot * 3 * Cc * 2);          // qkv bf16 / ywo f32 / f2o f32
    __hip_bfloat16* wot   = (__hip_bfloat16*)alloc((size_t)Cc * Cc * 2);
    __hip_bfloat16* yln   = (__hip_bfloat16*)alloc((size_t)Mtot * Cc * 2);
    __hip_bfloat16* w1b   = (__hip_bfloat16*)alloc((size_t)Cff * Cc * 2);
    __hip_bfloat16* mid   = (__hip_bfloat16*)alloc((size_t)Mtot * Cff * 2);
    __hip_bfloat16* w2b   = (__hip_bfloat16*)alloc((size_t)Cff * Cc * 2);

    __hip_bfloat16* qkv  = (__hip_bfloat16*)big;   // live: QKV gemm -> attn
    __hip_bfloat16* aout = xlb;                    // live after xlb dead (post QKV gemm)
    float*          ywo  = (float*)big;            // live after qkv dead (post attn)
    float*          f2o  = (float*)big;            // live after ywo dead (post LN1)

    if (ws_size < off) {
        sentinel_kernel<<<1, 256, 0, stream>>>((float*)d_out, (float)off * 1e-6f);
        return;
    }

    transpose_in<<<dim3(HW / 32, Cc / 32, Bn), dim3(32, 8), 0, stream>>>(x, xl, xlb);
    repack_qkvt<<<(3 * Cc * Cc + 255) / 256, 256, 0, stream>>>(WQ, WK, WV, wqkvt);
    repack_wot<<<(Cc * Cc + 255) / 256, 256, 0, stream>>>(WO, wot);
    cast_bf16<<<(Cff * Cc + 255) / 256, 256, 0, stream>>>(f1w, w1b, Cff * Cc);
    cast_bf16<<<(Cff * Cc + 255) / 256, 256, 0, stream>>>(f2w, w2b, Cff * Cc);

    // QKV: (M x 288) * (288 x 864) -> bf16
    gemm_mfma<true, false, false><<<dim3(864 / 96, Mtot / 128), 256, 0, stream>>>(
        xlb, wqkvt, nullptr, qkv, Mtot, 3 * Cc, Cc);

    // attention (border rows of aout = 0 implements the zero-pad)
    hipMemsetAsync(aout, 0, (size_t)Mtot * Cc * 2, stream);
    attn_kernel<<<(16928 * 9 * 32) / 256, 256, 0, stream>>>(qkv, aout);

    // W_O: (M x 288) * (288 x 288) -> f32
    gemm_mfma<false, false, false><<<dim3(Cc / 96, Mtot / 128), 256, 0, stream>>>(
        aout, wot, nullptr, ywo, Mtot, Cc, Cc);

    // LN1 + ReLU -> bf16
    ln_relu<<<Mtot / 4, 256, 0, stream>>>(ywo, g1, b1, yln);

    // FFN1: (M x 288) * (288 x 2592) + bias, relu -> bf16
    gemm_mfma<true, true, true><<<dim3(Cff / 96, Mtot / 128), 256, 0, stream>>>(
        yln, w1b, f1b, mid, Mtot, Cff, Cc);

    // FFN2: (M x 2592) * (2592 x 288) + bias -> f32
    gemm_mfma<false, true, false><<<dim3(Cc / 96, Mtot / 128), 256, 0, stream>>>(
        mid, w2b, f2b, f2o, Mtot, Cc, Cff);

    // LN2 + residual + ReLU + transpose to (B, C, H, W)
    final_kernel<<<Mtot / 4, 256, 0, stream>>>(f2o, xl, g2, b2, (float*)d_out);
}